// Round 1
// baseline (403.353 us; speedup 1.0000x reference)
//
#include <hip/hip_runtime.h>
#include <math.h>

#define T_DIM 4096
#define D_DIM 256
#define K_NUM 1024
#define B_NUM 16
#define N_TOT (B_NUM * T_DIM)   // 65536
#define EPS_FLAG 0.35f          // fp16 single-pass: pair-gap err std ~0.018 -> ~19 sigma

typedef float f32x4 __attribute__((ext_vector_type(4)));
typedef _Float16 half8 __attribute__((ext_vector_type(8)));

// ---------------- ws layout (bytes) ----------------
#define WS_FLAGCNT 0
#define WS_LOSS 4
#define WS_HIST 64
#define WS_E2 4352
#define WS_QIDX 8704            // 256 KB
#define WS_FLAGLIST 270848      // 256 KB
#define WS_BESTD 532992         // 256 KB (approx d2 for flagged rows)
#define WS_ESWZ 795136          // 512 KB: fp16 embed, fragment-swizzled

// async 16B global->LDS (no VGPR roundtrip). LDS dest is wave-uniform base + lane*16.
__device__ inline void gl_lds16(const void* g, void* l) {
    __builtin_amdgcn_global_load_lds(
        (const __attribute__((address_space(1))) unsigned int*)g,
        (__attribute__((address_space(3))) unsigned int*)l, 16, 0, 0);
}

// ---------------- kernel: |e_k|^2 (exact fp32) ----------------
__global__ __launch_bounds__(256) void e2_kernel(const float* __restrict__ embed,
                                                 float* __restrict__ e2) {
    const int wave = threadIdx.x >> 6;
    const int lane = threadIdx.x & 63;
    const int k = blockIdx.x * 4 + wave;
    const float4* row = (const float4*)(embed + (size_t)k * D_DIM);
    float4 v = row[lane];
    float s = v.x * v.x + v.y * v.y + v.z * v.z + v.w * v.w;
    #pragma unroll
    for (int off = 32; off; off >>= 1) s += __shfl_down(s, off);
    if (lane == 0) e2[k] = s;
}

// ---------------- kernel: embed -> fp16, fragment-swizzled ----------------
// 16-col group g (8192 B): k 0..7 of 1 KB each. lane l -> 16 B:
// col=g*16+(l&15), d=k*32+(l>>4)*8+j  (B-fragment layout, same geometry as bf16)
__global__ __launch_bounds__(256) void prep_eswz_kernel(const float* __restrict__ embed,
                                                        unsigned char* __restrict__ eswz) {
    const int tau = blockIdx.x * 256 + threadIdx.x;   // 0..32767
    const int g = tau >> 9;
    const int k = (tau >> 6) & 7;
    const int l = tau & 63;
    const int col = g * 16 + (l & 15);
    const int d0 = k * 32 + ((l >> 4) << 3);
    const float* src = embed + (size_t)col * D_DIM + d0;
    half8 h;
    #pragma unroll
    for (int j = 0; j < 8; ++j) h[j] = (_Float16)src[j];   // RTN v_cvt_f16_f32
    *(half8*)(eswz + (size_t)g * 8192 + k * 1024 + l * 16) = h;
}

// ---------------- kernel: fp16 MFMA distance + top-2 argmin + loss/x2 ----------------
// 512 blocks x 256 thr. Block: 128 rows x all 1024 cols; wave: 32 rows (2 frags).
// 32 chunks of 32 cols; async global_load_lds double-buffer; 1 barrier/chunk.
// Single fp16 pass (4 MFMA per k-step), exact e2, loss accumulated here.
__global__ __launch_bounds__(256, 2) void argmin_mfma_kernel(
    const float* __restrict__ x, const unsigned char* __restrict__ eswz,
    const float* __restrict__ e2, int* __restrict__ qidx,
    int* __restrict__ flagcnt, int* __restrict__ flaglist,
    float* __restrict__ bestd, float* __restrict__ loss_sum)
{
    __shared__ __align__(16) unsigned char bbuf[2][16384];
    __shared__ float e2s[K_NUM];

    const int tid = threadIdx.x;
    const int w = tid >> 6;
    const int l = tid & 63;
    const int rb = blockIdx.x * 128;
    const int b = rb >> 12;
    const float* xb = x + (size_t)b * (D_DIM * T_DIM);

    // issue chunk 0 (overlaps A conversion below)
    {
        const unsigned char* src = eswz + (size_t)tid * 16;
        #pragma unroll
        for (int r = 0; r < 4; ++r) gl_lds16(src + r * 4096, &bbuf[0][tid * 16 + r * 4096]);
    }
    for (int i = tid; i < K_NUM; i += 256) e2s[i] = e2[i];

    // ---- load + convert A fragments (fp16) + exact |x|^2 per row ----
    half8 Ah[2][8];
    float x2v[2];
    #pragma unroll
    for (int f = 0; f < 2; ++f) {
        const int row = rb + w * 32 + f * 16 + (l & 15);
        const int t = row & (T_DIM - 1);
        const float* xp = xb + t;
        float s2 = 0.f;
        #pragma unroll
        for (int k = 0; k < 8; ++k) {
            const int d0 = k * 32 + ((l >> 4) << 3);
            half8 h;
            #pragma unroll
            for (int j = 0; j < 8; ++j) {
                float v = xp[(size_t)(d0 + j) * T_DIM];
                h[j] = (_Float16)v;
                s2 = fmaf(v, v, s2);
            }
            Ah[f][k] = h;
        }
        x2v[f] = s2;   // this lane's 64 dims of its row
    }
    #pragma unroll
    for (int f = 0; f < 2; ++f) {   // full 256-dim |x|^2: reduce over the 4 replica lanes
        x2v[f] += __shfl_xor(x2v[f], 16);
        x2v[f] += __shfl_xor(x2v[f], 32);
    }
    __syncthreads();   // drains chunk-0 loads (vmcnt) + e2s

    float bestv[8], secv[8];
    int   besti[8];
    #pragma unroll
    for (int s = 0; s < 8; ++s) { bestv[s] = 3.4e38f; secv[s] = 3.4e38f; besti[s] = 0x7FFFFFFF; }

    for (int g = 0; g < 32; ++g) {
        if (g + 1 < 32) {   // async prefetch next chunk into the other buffer
            const unsigned char* src = eswz + (size_t)(g + 1) * 16384 + (size_t)tid * 16;
            unsigned char* dst = &bbuf[(g + 1) & 1][tid * 16];
            #pragma unroll
            for (int r = 0; r < 4; ++r) gl_lds16(src + r * 4096, dst + r * 4096);
        }
        const unsigned char* bb = bbuf[g & 1];

        f32x4 a00 = {0.f,0.f,0.f,0.f}, a01 = {0.f,0.f,0.f,0.f};
        f32x4 a10 = {0.f,0.f,0.f,0.f}, a11 = {0.f,0.f,0.f,0.f};
        #pragma unroll
        for (int k = 0; k < 8; ++k) {
            half8 b0 = *(const half8*)(bb + k * 1024 + l * 16);
            half8 b1 = *(const half8*)(bb + 8192 + k * 1024 + l * 16);
            a00 = __builtin_amdgcn_mfma_f32_16x16x32_f16(Ah[0][k], b0, a00, 0, 0, 0);
            a10 = __builtin_amdgcn_mfma_f32_16x16x32_f16(Ah[1][k], b0, a10, 0, 0, 0);
            a01 = __builtin_amdgcn_mfma_f32_16x16x32_f16(Ah[0][k], b1, a01, 0, 0, 0);
            a11 = __builtin_amdgcn_mfma_f32_16x16x32_f16(Ah[1][k], b1, a11, 0, 0, 0);
        }

        const int col0 = g * 32 + (l & 15);
        const float e2a = e2s[col0];
        const float e2b = e2s[col0 + 16];
        #pragma unroll
        for (int f = 0; f < 2; ++f) {
            const f32x4 accA = f ? a10 : a00;
            const f32x4 accB = f ? a11 : a01;
            #pragma unroll
            for (int r = 0; r < 4; ++r) {
                const int s = f * 4 + r;
                float sA = fmaf(-2.f, accA[r], e2a);
                float sB = fmaf(-2.f, accB[r], e2b);
                bool swp = sB < sA;
                float lo = swp ? sB : sA;
                float hi = swp ? sA : sB;
                int   li = swp ? col0 + 16 : col0;
                bool upd = lo < bestv[s];
                float mx = upd ? bestv[s] : lo;      // max(bestv, lo)
                bestv[s] = upd ? lo : bestv[s];
                besti[s] = upd ? li : besti[s];
                secv[s] = fminf(secv[s], fminf(mx, hi));
            }
        }
        __syncthreads();   // drains my prefetch for g+1; protects both buffers
    }

    // merge top-2 across the 16 lanes sharing each row; emit qidx/flag/loss
    float lossw = 0.f;
    #pragma unroll
    for (int slot = 0; slot < 8; ++slot) {
        float bv = bestv[slot], sv = secv[slot];
        int bi = besti[slot];
        #pragma unroll
        for (int d = 1; d < 16; d <<= 1) {
            float ob = __shfl_xor(bv, d);
            int   oi = __shfl_xor(bi, d);
            float os = __shfl_xor(sv, d);
            bool take = (ob < bv) || (ob == bv && oi < bi);
            float loser = take ? bv : ob;
            bv = take ? ob : bv;
            bi = take ? oi : bi;
            sv = fminf(fminf(sv, os), loser);
        }
        // fetch exact |x|^2 of this slot's row (held by lane (l&15)==rowlow)
        const int srcl = ((l >> 4) << 2) + (slot & 3);
        const float x2r = __shfl(x2v[slot >> 2], srcl);
        if ((l & 15) == 0) {
            const int row = rb + w * 32 + (slot >> 2) * 16 + (l >> 4) * 4 + (slot & 3);
            qidx[row] = bi;
            lossw += bv + x2r;   // |x-e|^2 = (e2 - 2 x.e) + |x|^2  (approx; cleanup corrects flagged)
            if (sv - bv < EPS_FLAG) {
                bestd[row] = bv;
                int p = atomicAdd(flagcnt, 1);
                flaglist[p] = row;
            }
        }
    }
    lossw += __shfl_down(lossw, 16);
    lossw += __shfl_down(lossw, 32);
    if (l == 0) atomicAdd(loss_sum, lossw);
}

// ---------------- kernel: exact fp32 re-resolve, 8 flagged rows per block-pass ----------------
// Shares one codebook stream across 8 rows (8x less L2 traffic than row-at-a-time).
// Also patches loss_sum with (exact - approx) delta per flagged row.
__global__ __launch_bounds__(256) void cleanup_kernel(
    const float* __restrict__ x, const float* __restrict__ embed,
    const float* __restrict__ e2, const int* __restrict__ flagcnt,
    const int* __restrict__ flaglist, int* __restrict__ qidx,
    const float* __restrict__ bestd, float* __restrict__ loss_sum)
{
    __shared__ float xr[8][256];
    __shared__ float rvall[8][256];
    __shared__ int   rixall[8][256];
    const int tid = threadIdx.x;
    int cnt = flagcnt[0];
    if (cnt > N_TOT) cnt = N_TOT;
    for (int base = blockIdx.x * 8; base < cnt; base += gridDim.x * 8) {
        const int nr = (cnt - base < 8) ? (cnt - base) : 8;
        __syncthreads();   // protect LDS reuse across iterations
        #pragma unroll
        for (int r = 0; r < 8; ++r) {
            float v = 0.f;
            if (r < nr) {
                const int row = flaglist[base + r];
                const int bb = row >> 12, t = row & (T_DIM - 1);
                v = x[(size_t)bb * (D_DIM * T_DIM) + (size_t)tid * T_DIM + t];
            }
            xr[r][tid] = v;
        }
        __syncthreads();

        float bv[8]; int bix[8];
        #pragma unroll
        for (int r = 0; r < 8; ++r) { bv[r] = 3.4e38f; bix[r] = 0x7FFFFFFF; }
        for (int q = 0; q < 4; ++q) {
            const int c = q * 256 + tid;
            const float4* ep = (const float4*)(embed + (size_t)c * D_DIM);
            float acc[8];
            #pragma unroll
            for (int r = 0; r < 8; ++r) acc[r] = 0.f;
            #pragma unroll 4
            for (int dd = 0; dd < 64; ++dd) {
                const float4 ev = ep[dd];
                #pragma unroll
                for (int r = 0; r < 8; ++r) {
                    const float4 xv = *(const float4*)&xr[r][dd * 4];
                    acc[r] = fmaf(ev.x, xv.x, acc[r]);
                    acc[r] = fmaf(ev.y, xv.y, acc[r]);
                    acc[r] = fmaf(ev.z, xv.z, acc[r]);
                    acc[r] = fmaf(ev.w, xv.w, acc[r]);
                }
            }
            const float ec = e2[c];
            #pragma unroll
            for (int r = 0; r < 8; ++r) {
                const float s = fmaf(-2.f, acc[r], ec);
                if (s < bv[r] || (s == bv[r] && c < bix[r])) { bv[r] = s; bix[r] = c; }
            }
        }
        #pragma unroll
        for (int r = 0; r < 8; ++r) { rvall[r][tid] = bv[r]; rixall[r][tid] = bix[r]; }
        __syncthreads();
        const int w = tid >> 6, ll = tid & 63;
        #pragma unroll
        for (int rr = 0; rr < 2; ++rr) {
            const int r = w * 2 + rr;
            float mv = 3.4e38f; int mi = 0x7FFFFFFF;
            #pragma unroll
            for (int j = 0; j < 4; ++j) {
                const float v = rvall[r][ll + j * 64];
                const int i2 = rixall[r][ll + j * 64];
                if (v < mv || (v == mv && i2 < mi)) { mv = v; mi = i2; }
            }
            #pragma unroll
            for (int d = 1; d < 64; d <<= 1) {
                const float ov = __shfl_xor(mv, d);
                const int   oi = __shfl_xor(mi, d);
                if (ov < mv || (ov == mv && oi < mi)) { mv = ov; mi = oi; }
            }
            if (ll == 0 && r < nr) {
                const int row = flaglist[base + r];
                qidx[row] = mi;
                atomicAdd(loss_sum, mv - bestd[row]);   // replace approx d2 with exact
            }
        }
    }
}

// ---------------- kernel: pure gather z_q + histogram (x no longer read) ----------------
__global__ __launch_bounds__(256) void gather_kernel(
    const float* __restrict__ embed, const int* __restrict__ qidx,
    float* __restrict__ out, int* __restrict__ hist)
{
    const int tid = threadIdx.x;
    const int n = blockIdx.x * 256 + tid;          // global t index 0..65535
    const int b = n >> 12, t = n & (T_DIM - 1);
    const int d0 = blockIdx.y * 64;
    const int idx = qidx[n];
    if (blockIdx.y == 0) atomicAdd(&hist[idx], 1);

    const float4* ep = (const float4*)(embed + (size_t)idx * D_DIM + d0);
    float*        op = out + (size_t)b * (D_DIM * T_DIM) + (size_t)d0 * T_DIM + t;
    #pragma unroll 4
    for (int i = 0; i < 16; ++i) {
        const float4 ev = ep[i];
        const size_t dd = (size_t)i * 4;
        op[(dd + 0) * T_DIM] = ev.x;
        op[(dd + 1) * T_DIM] = ev.y;
        op[(dd + 2) * T_DIM] = ev.z;
        op[(dd + 3) * T_DIM] = ev.w;
    }
}

// ---------------- kernel: entropy / finalize ----------------
__global__ __launch_bounds__(256) void finalize_kernel(
    const int* __restrict__ hist, const float* __restrict__ loss_sum,
    float* __restrict__ out)
{
    const int tid = threadIdx.x;
    float acc = 0.f;
    #pragma unroll
    for (int i = tid; i < K_NUM; i += 256) {
        const float p = (float)hist[i] * (1.f / (float)N_TOT);
        acc += p * logf(p + 1e-10f);
    }
    #pragma unroll
    for (int off = 32; off; off >>= 1) acc += __shfl_down(acc, off);
    __shared__ float ls[4];
    if ((tid & 63) == 0) ls[tid >> 6] = acc;
    __syncthreads();
    if (tid == 0) {
        const float H = -(ls[0] + ls[1] + ls[2] + ls[3]);
        const size_t base = (size_t)N_TOT * D_DIM;   // 16777216
        out[base] = 1.25f * loss_sum[0] * (1.f / 16777216.f);
        const float kld = (float)(6.931471805599453 * 4096.0);  // log(1024)*T
        #pragma unroll
        for (int i = 0; i < 16; ++i) out[base + 1 + i] = kld;
        out[base + 17] = expf(H);
    }
}

extern "C" void kernel_launch(void* const* d_in, const int* in_sizes, int n_in,
                              void* d_out, int out_size, void* d_ws, size_t ws_size,
                              hipStream_t stream)
{
    const float* x     = (const float*)d_in[0];   // (16, 256, 4096) f32
    const float* embed = (const float*)d_in[1];   // (1024, 256) f32
    float* out = (float*)d_out;

    char* ws = (char*)d_ws;
    int*   flagcnt  = (int*)(ws + WS_FLAGCNT);
    float* loss_sum = (float*)(ws + WS_LOSS);
    int*   hist     = (int*)(ws + WS_HIST);
    float* e2       = (float*)(ws + WS_E2);
    int*   qidx     = (int*)(ws + WS_QIDX);
    int*   flaglist = (int*)(ws + WS_FLAGLIST);
    float* bestd    = (float*)(ws + WS_BESTD);
    unsigned char* eswz = (unsigned char*)(ws + WS_ESWZ);

    hipMemsetAsync(ws, 0, 4160, stream);  // flagcnt + loss_sum + hist

    e2_kernel<<<K_NUM / 4, 256, 0, stream>>>(embed, e2);
    prep_eswz_kernel<<<128, 256, 0, stream>>>(embed, eswz);
    argmin_mfma_kernel<<<N_TOT / 128, 256, 0, stream>>>(x, eswz, e2, qidx, flagcnt, flaglist,
                                                        bestd, loss_sum);
    cleanup_kernel<<<256, 256, 0, stream>>>(x, embed, e2, flagcnt, flaglist, qidx,
                                            bestd, loss_sum);
    gather_kernel<<<dim3(N_TOT / 256, 4), 256, 0, stream>>>(embed, qidx, out, hist);
    finalize_kernel<<<1, 256, 0, stream>>>(hist, loss_sum, out);
}

// Round 2
// 288.860 us; speedup vs baseline: 1.3964x; 1.3964x over previous
//
#include <hip/hip_runtime.h>
#include <math.h>

#define T_DIM 4096
#define D_DIM 256
#define K_NUM 1024
#define B_NUM 16
#define N_TOT (B_NUM * T_DIM)   // 65536
#define EPS_FLAG 0.25f          // fp16 pair-gap err std ~0.025 -> 10 sigma

typedef float f32x4 __attribute__((ext_vector_type(4)));
typedef _Float16 half8 __attribute__((ext_vector_type(8)));

// ---------------- ws layout (bytes) ----------------
#define WS_FLAGCNT 0
#define WS_LOSS 4
#define WS_HIST 64
#define WS_E2 4352
#define WS_QIDX 8704            // 256 KB
#define WS_FLAGLIST 270848      // 256 KB
#define WS_BESTD 532992         // 256 KB (approx d2 per flag slot)
#define WS_ESWZ 795136          // 512 KB: fp16 embed, fragment-swizzled
#define WS_XROWS 1319424        // cap x 1 KB compact fp32 rows for flagged entries

// async 16B global->LDS (no VGPR roundtrip). LDS dest is wave-uniform base + lane*16.
__device__ inline void gl_lds16(const void* g, void* l) {
    __builtin_amdgcn_global_load_lds(
        (const __attribute__((address_space(1))) unsigned int*)g,
        (__attribute__((address_space(3))) unsigned int*)l, 16, 0, 0);
}

// ---------------- kernel: |e_k|^2 (exact fp32) ----------------
__global__ __launch_bounds__(256) void e2_kernel(const float* __restrict__ embed,
                                                 float* __restrict__ e2) {
    const int wave = threadIdx.x >> 6;
    const int lane = threadIdx.x & 63;
    const int k = blockIdx.x * 4 + wave;
    const float4* row = (const float4*)(embed + (size_t)k * D_DIM);
    float4 v = row[lane];
    float s = v.x * v.x + v.y * v.y + v.z * v.z + v.w * v.w;
    #pragma unroll
    for (int off = 32; off; off >>= 1) s += __shfl_down(s, off);
    if (lane == 0) e2[k] = s;
}

// ---------------- kernel: embed -> fp16, fragment-swizzled ----------------
// 16-col group g (8192 B): k 0..7 of 1 KB each. lane l -> 16 B:
// col=g*16+(l&15), d=k*32+(l>>4)*8+j  (B-fragment layout)
__global__ __launch_bounds__(256) void prep_eswz_kernel(const float* __restrict__ embed,
                                                        unsigned char* __restrict__ eswz) {
    const int tau = blockIdx.x * 256 + threadIdx.x;   // 0..32767
    const int g = tau >> 9;
    const int k = (tau >> 6) & 7;
    const int l = tau & 63;
    const int col = g * 16 + (l & 15);
    const int d0 = k * 32 + ((l >> 4) << 3);
    const float* src = embed + (size_t)col * D_DIM + d0;
    half8 h;
    #pragma unroll
    for (int j = 0; j < 8; ++j) h[j] = (_Float16)src[j];
    *(half8*)(eswz + (size_t)g * 8192 + k * 1024 + l * 16) = h;
}

// ---------------- kernel: fp16 MFMA distance + top-2 argmin + fused z_q/hist/loss ----------------
// 512 blocks x 256 thr. Block: 128 consecutive rows x all 1024 cols.
// Epilogues: (a) compact x-row copy for flagged rows (L2-hot), (b) z_q tile gather+write.
__global__ __launch_bounds__(256, 2) void argmin_mfma_kernel(
    const float* __restrict__ x, const unsigned char* __restrict__ eswz,
    const float* __restrict__ e2, const float* __restrict__ embed,
    int* __restrict__ qidx, int* __restrict__ flagcnt, int* __restrict__ flaglist,
    float* __restrict__ bestd, float* __restrict__ xrows,
    float* __restrict__ out, int* __restrict__ hist,
    float* __restrict__ loss_sum, int cap)
{
    __shared__ __align__(16) unsigned char bbuf[2][16384];
    __shared__ float e2s[K_NUM];
    __shared__ int   qid_lds[128];
    __shared__ int   lrows[128];
    __shared__ float lbest[128];
    __shared__ int   lcnt;
    __shared__ int   gbase;

    const int tid = threadIdx.x;
    const int w = tid >> 6;
    const int l = tid & 63;
    const int rb = blockIdx.x * 128;
    const int b = rb >> 12;
    const float* xb = x + (size_t)b * (D_DIM * T_DIM);
    if (tid == 0) lcnt = 0;

    // issue chunk 0 (overlaps A conversion below)
    {
        const unsigned char* src = eswz + (size_t)tid * 16;
        #pragma unroll
        for (int r = 0; r < 4; ++r) gl_lds16(src + r * 4096, &bbuf[0][tid * 16 + r * 4096]);
    }
    for (int i = tid; i < K_NUM; i += 256) e2s[i] = e2[i];

    // ---- load + convert A fragments (fp16) + exact |x|^2 per row ----
    half8 Ah[2][8];
    float x2v[2];
    #pragma unroll
    for (int f = 0; f < 2; ++f) {
        const int row = rb + w * 32 + f * 16 + (l & 15);
        const int t = row & (T_DIM - 1);
        const float* xp = xb + t;
        float s2 = 0.f;
        #pragma unroll
        for (int k = 0; k < 8; ++k) {
            const int d0 = k * 32 + ((l >> 4) << 3);
            half8 h;
            #pragma unroll
            for (int j = 0; j < 8; ++j) {
                float v = xp[(size_t)(d0 + j) * T_DIM];
                h[j] = (_Float16)v;
                s2 = fmaf(v, v, s2);
            }
            Ah[f][k] = h;
        }
        x2v[f] = s2;
    }
    #pragma unroll
    for (int f = 0; f < 2; ++f) {   // full 256-dim |x|^2 across the 4 replica lanes
        x2v[f] += __shfl_xor(x2v[f], 16);
        x2v[f] += __shfl_xor(x2v[f], 32);
    }
    __syncthreads();   // drains chunk-0 loads (vmcnt) + e2s; lcnt=0 visible

    float bestv[8], secv[8];
    int   besti[8];
    #pragma unroll
    for (int s = 0; s < 8; ++s) { bestv[s] = 3.4e38f; secv[s] = 3.4e38f; besti[s] = 0x7FFFFFFF; }

    for (int g = 0; g < 32; ++g) {
        if (g + 1 < 32) {
            const unsigned char* src = eswz + (size_t)(g + 1) * 16384 + (size_t)tid * 16;
            unsigned char* dst = &bbuf[(g + 1) & 1][tid * 16];
            #pragma unroll
            for (int r = 0; r < 4; ++r) gl_lds16(src + r * 4096, dst + r * 4096);
        }
        const unsigned char* bb = bbuf[g & 1];

        f32x4 a00 = {0.f,0.f,0.f,0.f}, a01 = {0.f,0.f,0.f,0.f};
        f32x4 a10 = {0.f,0.f,0.f,0.f}, a11 = {0.f,0.f,0.f,0.f};
        #pragma unroll
        for (int k = 0; k < 8; ++k) {
            half8 b0 = *(const half8*)(bb + k * 1024 + l * 16);
            half8 b1 = *(const half8*)(bb + 8192 + k * 1024 + l * 16);
            a00 = __builtin_amdgcn_mfma_f32_16x16x32_f16(Ah[0][k], b0, a00, 0, 0, 0);
            a10 = __builtin_amdgcn_mfma_f32_16x16x32_f16(Ah[1][k], b0, a10, 0, 0, 0);
            a01 = __builtin_amdgcn_mfma_f32_16x16x32_f16(Ah[0][k], b1, a01, 0, 0, 0);
            a11 = __builtin_amdgcn_mfma_f32_16x16x32_f16(Ah[1][k], b1, a11, 0, 0, 0);
        }

        const int col0 = g * 32 + (l & 15);
        const float e2a = e2s[col0];
        const float e2b = e2s[col0 + 16];
        #pragma unroll
        for (int f = 0; f < 2; ++f) {
            const f32x4 accA = f ? a10 : a00;
            const f32x4 accB = f ? a11 : a01;
            #pragma unroll
            for (int r = 0; r < 4; ++r) {
                const int s = f * 4 + r;
                float sA = fmaf(-2.f, accA[r], e2a);
                float sB = fmaf(-2.f, accB[r], e2b);
                bool swp = sB < sA;
                float lo = swp ? sB : sA;
                float hi = swp ? sA : sB;
                int   li = swp ? col0 + 16 : col0;
                bool upd = lo < bestv[s];
                float mx = upd ? bestv[s] : lo;
                bestv[s] = upd ? lo : bestv[s];
                besti[s] = upd ? li : besti[s];
                secv[s] = fminf(secv[s], fminf(mx, hi));
            }
        }
        __syncthreads();
    }

    // merge top-2 across the 16 lanes sharing each row; emit qidx/hist/flag/loss
    float lossw = 0.f;
    #pragma unroll
    for (int slot = 0; slot < 8; ++slot) {
        float bv = bestv[slot], sv = secv[slot];
        int bi = besti[slot];
        #pragma unroll
        for (int d = 1; d < 16; d <<= 1) {
            float ob = __shfl_xor(bv, d);
            int   oi = __shfl_xor(bi, d);
            float os = __shfl_xor(sv, d);
            bool take = (ob < bv) || (ob == bv && oi < bi);
            float loser = take ? bv : ob;
            bv = take ? ob : bv;
            bi = take ? oi : bi;
            sv = fminf(fminf(sv, os), loser);
        }
        const int srcl = ((l >> 4) << 2) + (slot & 3);
        const float x2r = __shfl(x2v[slot >> 2], srcl);
        if ((l & 15) == 0) {
            const int rloc = w * 32 + (slot >> 2) * 16 + (l >> 4) * 4 + (slot & 3);
            qidx[rb + rloc] = bi;
            qid_lds[rloc] = bi;
            atomicAdd(&hist[bi], 1);
            lossw += bv + x2r;   // approx d2 + exact |x|^2 (cleanup patches flagged)
            if (sv - bv < EPS_FLAG) {
                int lp = atomicAdd(&lcnt, 1);
                lrows[lp] = rb + rloc;
                lbest[lp] = bv;
            }
        }
    }
    lossw += __shfl_down(lossw, 16);
    lossw += __shfl_down(lossw, 32);
    if (l == 0) atomicAdd(loss_sum, lossw);

    // ---- epilogue a: compact x-row copies for flagged rows (reads are L2-hot) ----
    __syncthreads();
    const int nloc = lcnt;
    if (tid == 0) gbase = nloc ? atomicAdd(flagcnt, nloc) : 0;
    __syncthreads();
    for (int i = w; i < nloc; i += 4) {        // one wave per flagged row
        const int row = lrows[i];
        const int p = gbase + i;
        const bool have = (p < cap);
        if (have) {
            const float* xp = xb + (row & (T_DIM - 1));
            float4 vv;
            vv.x = xp[(size_t)(l * 4 + 0) * T_DIM];
            vv.y = xp[(size_t)(l * 4 + 1) * T_DIM];
            vv.z = xp[(size_t)(l * 4 + 2) * T_DIM];
            vv.w = xp[(size_t)(l * 4 + 3) * T_DIM];
            *(float4*)(xrows + (size_t)p * D_DIM + l * 4) = vv;
        }
        if (l == 0) {
            flaglist[p] = have ? row : (row | 0x80000000);
            bestd[p] = lbest[i];
        }
    }

    // ---- epilogue b: fused z_q gather + coalesced write (tile [64 d][128 t] in bbuf) ----
    float* tile = (float*)bbuf;
    const int t0 = rb & (T_DIM - 1);
    float* outb = out + (size_t)b * (D_DIM * T_DIM);
    for (int c = 0; c < 4; ++c) {
        const int d0 = c * 64;
        __syncthreads();                       // tile free
        {
            const int r = tid & 127;
            const int half = tid >> 7;
            const int qi = qid_lds[r];
            const float4* ep = (const float4*)(embed + (size_t)qi * D_DIM + d0 + half * 32);
            #pragma unroll
            for (int i = 0; i < 8; ++i) {
                const float4 ev = ep[i];
                const int dl = half * 32 + i * 4;
                tile[(dl + 0) * 128 + r] = ev.x;
                tile[(dl + 1) * 128 + r] = ev.y;
                tile[(dl + 2) * 128 + r] = ev.z;
                tile[(dl + 3) * 128 + r] = ev.w;
            }
        }
        __syncthreads();
        #pragma unroll 4
        for (int j = 0; j < 32; ++j) {
            const int flat = j * 256 + tid;
            const int dl = flat >> 7;
            const int rr = flat & 127;
            outb[(size_t)(d0 + dl) * T_DIM + t0 + rr] = tile[dl * 128 + rr];
        }
    }
}

// ---------------- kernel: exact fp32 re-resolve (coalesced xrows), 8 rows/pass ----------------
// Patches qidx/z_q/hist only when the winner flips; always patches loss (exact - approx).
__global__ __launch_bounds__(256) void cleanup_kernel(
    const float* __restrict__ x, const float* __restrict__ xrows,
    const float* __restrict__ embed, const float* __restrict__ e2,
    const int* __restrict__ flagcnt, const int* __restrict__ flaglist,
    int* __restrict__ qidx, const float* __restrict__ bestd,
    float* __restrict__ loss_sum, float* __restrict__ out, int* __restrict__ hist)
{
    __shared__ float xr[8][256];
    __shared__ float rvall[8][256];
    __shared__ int   rixall[8][256];
    __shared__ int   rowss[8];
    const int tid = threadIdx.x;
    int cnt = flagcnt[0];
    if (cnt > N_TOT) cnt = N_TOT;
    for (int base = blockIdx.x * 8; base < cnt; base += gridDim.x * 8) {
        const int nr = (cnt - base < 8) ? (cnt - base) : 8;
        __syncthreads();
        if (tid < 8) rowss[tid] = (tid < nr) ? flaglist[base + tid] : 0;
        __syncthreads();
        #pragma unroll
        for (int r = 0; r < 8; ++r) {
            float v = 0.f;
            if (r < nr) {
                const int fe = rowss[r];
                if (fe >= 0) {
                    v = xrows[(size_t)(base + r) * D_DIM + tid];
                } else {   // slow path: no compact copy (cap overflow)
                    const int row = fe & 0x7FFFFFFF;
                    v = x[(size_t)(row >> 12) * (D_DIM * T_DIM) + (size_t)tid * T_DIM
                          + (row & (T_DIM - 1))];
                }
            }
            xr[r][tid] = v;
        }
        __syncthreads();

        float bv[8]; int bix[8];
        #pragma unroll
        for (int r = 0; r < 8; ++r) { bv[r] = 3.4e38f; bix[r] = 0x7FFFFFFF; }
        for (int q = 0; q < 4; ++q) {
            const int c = q * 256 + tid;
            const float4* ep = (const float4*)(embed + (size_t)c * D_DIM);
            float acc[8];
            #pragma unroll
            for (int r = 0; r < 8; ++r) acc[r] = 0.f;
            #pragma unroll 8
            for (int dd = 0; dd < 64; ++dd) {
                const float4 ev = ep[dd];
                #pragma unroll
                for (int r = 0; r < 8; ++r) {
                    const float4 xv = *(const float4*)&xr[r][dd * 4];
                    acc[r] = fmaf(ev.x, xv.x, acc[r]);
                    acc[r] = fmaf(ev.y, xv.y, acc[r]);
                    acc[r] = fmaf(ev.z, xv.z, acc[r]);
                    acc[r] = fmaf(ev.w, xv.w, acc[r]);
                }
            }
            const float ec = e2[c];
            #pragma unroll
            for (int r = 0; r < 8; ++r) {
                const float s = fmaf(-2.f, acc[r], ec);
                if (s < bv[r] || (s == bv[r] && c < bix[r])) { bv[r] = s; bix[r] = c; }
            }
        }
        #pragma unroll
        for (int r = 0; r < 8; ++r) { rvall[r][tid] = bv[r]; rixall[r][tid] = bix[r]; }
        __syncthreads();
        const int w = tid >> 6, ll = tid & 63;
        #pragma unroll
        for (int rr2 = 0; rr2 < 2; ++rr2) {
            const int r = w * 2 + rr2;
            float mv = 3.4e38f; int mi = 0x7FFFFFFF;
            #pragma unroll
            for (int j = 0; j < 4; ++j) {
                const float v = rvall[r][ll + j * 64];
                const int i2 = rixall[r][ll + j * 64];
                if (v < mv || (v == mv && i2 < mi)) { mv = v; mi = i2; }
            }
            #pragma unroll
            for (int d = 1; d < 64; d <<= 1) {
                const float ov = __shfl_xor(mv, d);
                const int   oi = __shfl_xor(mi, d);
                if (ov < mv || (ov == mv && oi < mi)) { mv = ov; mi = oi; }
            }
            if (r < nr) {
                const int row = rowss[r] & 0x7FFFFFFF;
                const int old = qidx[row];        // broadcast load
                if (mi != old) {                  // winner flipped: patch qidx/z_q/hist
                    const int b2 = row >> 12, t2 = row & (T_DIM - 1);
                    const float4 ev = *(const float4*)(embed + (size_t)mi * D_DIM + ll * 4);
                    float* op = out + (size_t)b2 * (D_DIM * T_DIM) + t2;
                    op[(size_t)(ll * 4 + 0) * T_DIM] = ev.x;
                    op[(size_t)(ll * 4 + 1) * T_DIM] = ev.y;
                    op[(size_t)(ll * 4 + 2) * T_DIM] = ev.z;
                    op[(size_t)(ll * 4 + 3) * T_DIM] = ev.w;
                    if (ll == 0) {
                        qidx[row] = mi;
                        atomicAdd(&hist[mi], 1);
                        atomicAdd(&hist[old], -1);
                    }
                }
                if (ll == 0) atomicAdd(loss_sum, mv - bestd[base + r]);
            }
        }
    }
}

// ---------------- kernel: entropy / finalize ----------------
__global__ __launch_bounds__(256) void finalize_kernel(
    const int* __restrict__ hist, const float* __restrict__ loss_sum,
    float* __restrict__ out)
{
    const int tid = threadIdx.x;
    float acc = 0.f;
    #pragma unroll
    for (int i = tid; i < K_NUM; i += 256) {
        const float p = (float)hist[i] * (1.f / (float)N_TOT);
        acc += p * logf(p + 1e-10f);
    }
    #pragma unroll
    for (int off = 32; off; off >>= 1) acc += __shfl_down(acc, off);
    __shared__ float ls[4];
    if ((tid & 63) == 0) ls[tid >> 6] = acc;
    __syncthreads();
    if (tid == 0) {
        const float H = -(ls[0] + ls[1] + ls[2] + ls[3]);
        const size_t base = (size_t)N_TOT * D_DIM;   // 16777216
        out[base] = 1.25f * loss_sum[0] * (1.f / 16777216.f);
        const float kld = (float)(6.931471805599453 * 4096.0);  // log(1024)*T
        #pragma unroll
        for (int i = 0; i < 16; ++i) out[base + 1 + i] = kld;
        out[base + 17] = expf(H);
    }
}

extern "C" void kernel_launch(void* const* d_in, const int* in_sizes, int n_in,
                              void* d_out, int out_size, void* d_ws, size_t ws_size,
                              hipStream_t stream)
{
    const float* x     = (const float*)d_in[0];   // (16, 256, 4096) f32
    const float* embed = (const float*)d_in[1];   // (1024, 256) f32
    float* out = (float*)d_out;

    char* ws = (char*)d_ws;
    int*   flagcnt  = (int*)(ws + WS_FLAGCNT);
    float* loss_sum = (float*)(ws + WS_LOSS);
    int*   hist     = (int*)(ws + WS_HIST);
    float* e2       = (float*)(ws + WS_E2);
    int*   qidx     = (int*)(ws + WS_QIDX);
    int*   flaglist = (int*)(ws + WS_FLAGLIST);
    float* bestd    = (float*)(ws + WS_BESTD);
    unsigned char* eswz = (unsigned char*)(ws + WS_ESWZ);
    float* xrows    = (float*)(ws + WS_XROWS);

    int cap = 0;
    if (ws_size > (size_t)WS_XROWS + 1024) {
        size_t c = (ws_size - WS_XROWS) / 1024;
        cap = (c > (size_t)N_TOT) ? N_TOT : (int)c;
    }

    hipMemsetAsync(ws, 0, 4160, stream);  // flagcnt + loss_sum + hist

    e2_kernel<<<K_NUM / 4, 256, 0, stream>>>(embed, e2);
    prep_eswz_kernel<<<128, 256, 0, stream>>>(embed, eswz);
    argmin_mfma_kernel<<<N_TOT / 128, 256, 0, stream>>>(x, eswz, e2, embed, qidx,
                                                        flagcnt, flaglist, bestd, xrows,
                                                        out, hist, loss_sum, cap);
    cleanup_kernel<<<512, 256, 0, stream>>>(x, xrows, embed, e2, flagcnt, flaglist,
                                            qidx, bestd, loss_sum, out, hist);
    finalize_kernel<<<1, 256, 0, stream>>>(hist, loss_sum, out);
}